// Round 1
// baseline (715.107 us; speedup 1.0000x reference)
//
#include <hip/hip_runtime.h>
#include <cstdint>
#include <cstddef>

#define NNODES 50000
#define NRELS  256
#define DIM    256
#define TT     24
#define EE     20000
#define BATCH  16
#define SEQQ   7

typedef __bf16 bf16;
typedef __bf16 bf16x8 __attribute__((ext_vector_type(8)));
typedef float  f32x4  __attribute__((ext_vector_type(4)));

// async global->LDS, 16B per lane; dest must be wave-uniform base (+lane*16 by HW)
__device__ __forceinline__ void gload16(const void* g, void* l){
  __builtin_amdgcn_global_load_lds((const __attribute__((address_space(1))) void*)g,
                                   (__attribute__((address_space(3))) void*)l, 16, 0, 0);
}

// ---------------- prep kernels ----------------

// fp32 -> bf16, 8 elems/thread
__global__ void k_cvt8(const float* __restrict__ in, bf16* __restrict__ out, int n8){
  int i = blockIdx.x*256 + threadIdx.x;
  if (i >= n8) return;
  const float4* p = (const float4*)in + (size_t)i*2;
  float4 a = p[0], b = p[1];
  bf16x8 o;
  o[0]=(bf16)a.x; o[1]=(bf16)a.y; o[2]=(bf16)a.z; o[3]=(bf16)a.w;
  o[4]=(bf16)b.x; o[5]=(bf16)b.y; o[6]=(bf16)b.z; o[7]=(bf16)b.w;
  ((bf16x8*)out)[i] = o;
}

// Fused edge weight, transposed: WbT[n][k], k in [0,768).
//  k<256:        W1[k][n]   = edge_w_W[k][n]           (src part)
//  k in [256,512): Wtf[k-256][n] = sum_m textW[k-256][m]*edge_w_W[256+m][n]  (text fold)
//  k>=512:       W3         = edge_w_W[k][n]           (dst part)
__global__ void k_build_wbt(const float* __restrict__ tW, const float* __restrict__ eW,
                            bf16* __restrict__ WbT){
  int n = blockIdx.x, j = threadIdx.x;
  WbT[(size_t)n*768 + j]       = (bf16)eW[(size_t)j*256 + n];
  WbT[(size_t)n*768 + 512 + j] = (bf16)eW[(size_t)(512+j)*256 + n];
  float acc = 0.f;
  for (int m=0; m<256; ++m) acc += tW[(size_t)j*256 + m] * eW[(size_t)(256+m)*256 + n];
  WbT[(size_t)n*768 + 256 + j] = (bf16)acc;
}

// fused bias: bfused[n] = edge_w_b[n] + sum_m text_w_b[m]*W2[m][n]
__global__ void k_bias(const float* __restrict__ tb, const float* __restrict__ eW,
                       const float* __restrict__ eb, float* __restrict__ bf){
  int n = threadIdx.x;
  float acc = eb[n];
  for (int m=0; m<256; ++m) acc += tb[m] * eW[(size_t)(256+m)*256 + n];
  bf[n] = acc;
}

// gru weight [256][768] -> transposed bf16 [768][256]
__global__ void k_gruWT(const float* __restrict__ W, bf16* __restrict__ WT){
  int n = blockIdx.x, k = threadIdx.x;
  WT[(size_t)n*256 + k] = (bf16)W[(size_t)k*768 + n];
}

// per-t histogram of rels + exclusive scan -> counts/offs/cursor
__global__ void k_hist(const int* __restrict__ rel, int* __restrict__ counts,
                       int* __restrict__ offs, int* __restrict__ cursor){
  __shared__ int hist[256];
  __shared__ int scan[256];
  int t = blockIdx.x, tid = threadIdx.x;
  hist[tid] = 0;
  __syncthreads();
  for (int e = tid; e < EE; e += 256) atomicAdd(&hist[rel[(size_t)t*EE + e]], 1);
  __syncthreads();
  int v = hist[tid];
  scan[tid] = v;
  __syncthreads();
  for (int d=1; d<256; d<<=1){
    int add = (tid >= d) ? scan[tid-d] : 0;
    __syncthreads();
    scan[tid] += add;
    __syncthreads();
  }
  int ex = scan[tid] - v;
  counts[t*256+tid] = v;
  offs[t*256+tid]   = ex;
  cursor[t*256+tid] = ex;
}

// bucket edge ids by (t, rel)
__global__ void k_perm(const int* __restrict__ rel, int* __restrict__ cursor,
                       int* __restrict__ perm){
  int t = blockIdx.y;
  int e = blockIdx.x*256 + threadIdx.x;
  if (e < EE){
    int r = rel[(size_t)t*EE + e];
    int p = atomicAdd(&cursor[t*256 + r], 1);
    perm[(size_t)t*EE + p] = e;
  }
}

// ---------------- edge GEMM + fused scatter-mean ----------------
// One block per (t, rel). M=96-row chunks (pad-masked), K=768, N=256.
// 4 waves, each wave owns 64 cols: frags mi in [0,6), ni in [0,4).
// LDS chunk swizzle: 16B chunk 'part' XOR ((row>>1)&3) applied on BOTH the
// staging source address and the ds_read address (involution) -> 2-way banks.
__global__ __launch_bounds__(256) void k_edge(
    const bf16* __restrict__ node_bf, const float* __restrict__ text_emb,
    const bf16* __restrict__ WbT, const float* __restrict__ bfused,
    const int* __restrict__ edge_src, const int* __restrict__ edge_dst,
    const int* __restrict__ counts, const int* __restrict__ offs,
    const int* __restrict__ perm, bf16* __restrict__ rel_bf)
{
  int r = blockIdx.x, t = blockIdx.y;
  int tid = threadIdx.x;
  int lane = tid & 63, w = tid >> 6;
  int tr = t*256 + r;
  int nE = counts[tr];
  if (nE == 0){
    rel_bf[(size_t)tr*256 + tid] = (bf16)0.f;
    return;
  }
  __shared__ __align__(16) bf16 Alds[96*32];    // 6KB
  __shared__ __align__(16) bf16 Blds[256*32];   // 16KB
  __shared__ float colsum[256];
  __shared__ int sI[96], dI[96], eI[96];
  colsum[tid] = 0.f;
  int base = offs[tr];
  int c0 = w*64;
  int l15 = lane & 15, lq = lane >> 4;
  float bias[4];
  #pragma unroll
  for (int ni=0; ni<4; ++ni) bias[ni] = bfused[c0 + ni*16 + l15];
  int nchunks = (nE + 95)/96;
  for (int ch=0; ch<nchunks; ++ch){
    int row0 = ch*96;
    __syncthreads();
    if (tid < 96){
      int rr = row0 + tid;
      int eid = (rr < nE) ? perm[(size_t)t*EE + base + rr] : 0;
      eI[tid] = eid;
      sI[tid] = edge_src[(size_t)t*EE + eid];
      dI[tid] = edge_dst[(size_t)t*EE + eid];
    }
    __syncthreads();
    f32x4 acc[6][4];
    f32x4 z4 = {0.f,0.f,0.f,0.f};
    #pragma unroll
    for (int mi=0;mi<6;++mi)
      #pragma unroll
      for (int ni=0;ni<4;++ni) acc[mi][ni] = z4;

    for (int ks=0; ks<24; ++ks){
      int k0 = ks*32;
      int region = ks >> 3;   // 0: src-gather, 1: text (cvt), 2: dst-gather
      if (region != 1){
        const int* idx = (region==0) ? sI : dI;
        int kb = (region==0) ? k0*2 : (k0-512)*2;
        { // pass 0: chunks 0..255 (rows 0..63)
          int c = tid;
          int rowA = c >> 2, part = c & 3;
          int pp = part ^ ((rowA>>1)&3);
          const char* src = (const char*)(node_bf + (size_t)idx[rowA]*256) + kb + pp*16;
          gload16(src, (char*)Alds + (size_t)(w*64)*16);
        }
        if (w < 2){ // pass 1: chunks 256..383 (rows 64..95), waves 0-1
          int c = 256 + tid;
          int rowA = c >> 2, part = c & 3;
          int pp = part ^ ((rowA>>1)&3);
          const char* src = (const char*)(node_bf + (size_t)idx[rowA]*256) + kb + pp*16;
          gload16(src, (char*)Alds + (size_t)(256 + w*64)*16);
        }
      } else {
        int kt = k0 - 256;
        #pragma unroll
        for (int p=0;p<2;++p){
          int c = p*256 + tid;
          if (c < 384){
            int rowA = c >> 2, part = c & 3;
            int pp = part ^ ((rowA>>1)&3);
            const float* src = text_emb + ((size_t)t*EE + eI[rowA])*256 + kt + pp*8;
            float4 u = *(const float4*)src;
            float4 v = *(const float4*)(src+4);
            bf16x8 o;
            o[0]=(bf16)u.x; o[1]=(bf16)u.y; o[2]=(bf16)u.z; o[3]=(bf16)u.w;
            o[4]=(bf16)v.x; o[5]=(bf16)v.y; o[6]=(bf16)v.z; o[7]=(bf16)v.w;
            *(bf16x8*)((char*)Alds + (size_t)c*16) = o;
          }
        }
      }
      // stage B: 256 cols x 32 k = 1024 chunks
      #pragma unroll
      for (int p=0;p<4;++p){
        int c = p*256 + tid;
        int nn = c >> 2, part = c & 3;
        int pp = part ^ ((nn>>1)&3);
        const char* src = (const char*)(WbT + (size_t)nn*768 + k0) + pp*16;
        gload16(src, (char*)Blds + (size_t)(p*256 + w*64)*16);
      }
      __syncthreads();
      bf16x8 a[6], b[4];
      #pragma unroll
      for (int mi=0;mi<6;++mi){
        int rowA = mi*16 + l15;
        a[mi] = *(const bf16x8*)((const char*)Alds + (size_t)rowA*64 + (size_t)((lq ^ ((rowA>>1)&3))*16));
      }
      #pragma unroll
      for (int ni=0;ni<4;++ni){
        int nn = c0 + ni*16 + l15;
        b[ni] = *(const bf16x8*)((const char*)Blds + (size_t)nn*64 + (size_t)((lq ^ ((nn>>1)&3))*16));
      }
      #pragma unroll
      for (int mi=0;mi<6;++mi)
        #pragma unroll
        for (int ni=0;ni<4;++ni)
          acc[mi][ni] = __builtin_amdgcn_mfma_f32_16x16x32_bf16(a[mi], b[ni], acc[mi][ni], 0, 0, 0);
      __syncthreads();
    }
    // epilogue: bias + relu + masked column reduce into LDS colsum
    #pragma unroll
    for (int ni=0;ni<4;++ni){
      float s = 0.f;
      #pragma unroll
      for (int mi=0;mi<6;++mi)
        #pragma unroll
        for (int q=0;q<4;++q){
          int rloc = mi*16 + lq*4 + q;
          if (row0 + rloc < nE){
            float v = acc[mi][ni][q] + bias[ni];
            s += fmaxf(v, 0.f);
          }
        }
      atomicAdd(&colsum[c0 + ni*16 + l15], s);
    }
  }
  __syncthreads();
  rel_bf[(size_t)tr*256 + tid] = (bf16)(colsum[tid] / (float)nE);
}

// ---------------- plain bf16 GEMM, K=256 fixed, N stride 768, + bias ----------------
// Out[m][n] = sum_k A[m][k]*BT[n][k] + bias[n]; tile 128x128, 4 waves 2x2.
__global__ __launch_bounds__(256) void k_gemm(
    const bf16* __restrict__ A, const bf16* __restrict__ BT,
    const float* __restrict__ bias, float* __restrict__ Out)
{
  int m0 = blockIdx.x*128, n0 = blockIdx.y*128;
  int tid = threadIdx.x, lane = tid&63, w = tid>>6;
  int l15 = lane&15, lq = lane>>4;
  __shared__ __align__(16) bf16 Al[128*32];
  __shared__ __align__(16) bf16 Bl[128*32];
  int wr = (w&1)*64, wc = (w>>1)*64;
  f32x4 acc[4][4];
  f32x4 z4 = {0.f,0.f,0.f,0.f};
  #pragma unroll
  for (int mi=0;mi<4;++mi)
    #pragma unroll
    for (int ni=0;ni<4;++ni) acc[mi][ni]=z4;
  for (int ks=0; ks<8; ++ks){
    int k0 = ks*32;
    #pragma unroll
    for (int p=0;p<2;++p){
      int c = p*256 + tid;
      int rw = c>>2, part = c&3;
      int pp = part ^ ((rw>>1)&3);
      const char* src = (const char*)(A + (size_t)(m0+rw)*256 + k0) + pp*16;
      gload16(src, (char*)Al + (size_t)(p*256 + w*64)*16);
    }
    #pragma unroll
    for (int p=0;p<2;++p){
      int c = p*256 + tid;
      int nn = c>>2, part = c&3;
      int pp = part ^ ((nn>>1)&3);
      const char* src = (const char*)(BT + (size_t)(n0+nn)*256 + k0) + pp*16;
      gload16(src, (char*)Bl + (size_t)(p*256 + w*64)*16);
    }
    __syncthreads();
    bf16x8 a[4], b[4];
    #pragma unroll
    for (int mi=0;mi<4;++mi){
      int rw = wr + mi*16 + l15;
      a[mi] = *(const bf16x8*)((const char*)Al + (size_t)rw*64 + (size_t)((lq ^ ((rw>>1)&3))*16));
    }
    #pragma unroll
    for (int ni=0;ni<4;++ni){
      int nn = wc + ni*16 + l15;
      b[ni] = *(const bf16x8*)((const char*)Bl + (size_t)nn*64 + (size_t)((lq ^ ((nn>>1)&3))*16));
    }
    #pragma unroll
    for (int mi=0;mi<4;++mi)
      #pragma unroll
      for (int ni=0;ni<4;++ni)
        acc[mi][ni] = __builtin_amdgcn_mfma_f32_16x16x32_bf16(a[mi], b[ni], acc[mi][ni], 0,0,0);
    __syncthreads();
  }
  #pragma unroll
  for (int ni=0;ni<4;++ni){
    int col = n0 + wc + ni*16 + l15;
    float bv = bias[col];
    #pragma unroll
    for (int mi=0;mi<4;++mi){
      #pragma unroll
      for (int q=0;q<4;++q){
        int row = m0 + wr + mi*16 + lq*4 + q;
        Out[(size_t)row*768 + col] = acc[mi][ni][q] + bv;
      }
    }
  }
}

// ---------------- GRU elementwise update ----------------
__global__ void k_update(const float* __restrict__ GI, const float* __restrict__ gh,
                         const float* __restrict__ bhh, const int* __restrict__ time_idx,
                         const float* __restrict__ h_in, float* __restrict__ h_out,
                         bf16* __restrict__ hbf_out, float* __restrict__ out_final, int s)
{
  int row = blockIdx.x;           // b*256 + r
  int d = threadIdx.x;
  int b = row >> 8, rr = row & 255;
  int t = time_idx[b*SEQQ + s];
  size_t gib = (size_t)(t*256 + rr)*768;
  float ir = GI[gib + d], iz = GI[gib + 256 + d], inn = GI[gib + 512 + d];
  float hr, hz, hn;
  if (s == 0){ hr = bhh[d]; hz = bhh[256+d]; hn = bhh[512+d]; }
  else { size_t gb = (size_t)row*768; hr = gh[gb+d]; hz = gh[gb+256+d]; hn = gh[gb+512+d]; }
  float rg = 1.f/(1.f + __expf(-(ir+hr)));
  float zz = 1.f/(1.f + __expf(-(iz+hz)));
  float nn = tanhf(inn + rg*hn);
  float hp = (s==0) ? 0.f : h_in[(size_t)row*256 + d];
  float hv = (1.f - zz)*nn + zz*hp;
  if (s == SEQQ-1){
    out_final[(size_t)row*256 + d] = hv;
  } else {
    h_out[(size_t)row*256 + d] = hv;
    hbf_out[(size_t)row*256 + d] = (bf16)hv;
  }
}

// ---------------- launch ----------------
extern "C" void kernel_launch(void* const* d_in, const int* in_sizes, int n_in,
                              void* d_out, int out_size, void* d_ws, size_t ws_size,
                              hipStream_t stream)
{
  (void)in_sizes; (void)n_in; (void)out_size; (void)ws_size;
  const float* node_embeds = (const float*)d_in[0];
  const float* text_emb    = (const float*)d_in[1];
  const float* text_w_W    = (const float*)d_in[2];
  const float* text_w_b    = (const float*)d_in[3];
  const float* edge_w_W    = (const float*)d_in[4];
  const float* edge_w_b    = (const float*)d_in[5];
  const float* gru_Wih     = (const float*)d_in[6];
  const float* gru_Whh     = (const float*)d_in[7];
  const float* gru_bih     = (const float*)d_in[8];
  const float* gru_bhh     = (const float*)d_in[9];
  const int* edge_src      = (const int*)d_in[10];
  const int* edge_dst      = (const int*)d_in[11];
  const int* edge_rel      = (const int*)d_in[12];
  const int* time_idx      = (const int*)d_in[13];
  float* out = (float*)d_out;
  char* ws = (char*)d_ws;

  size_t o = 0;
  bf16*  WbT    = (bf16*) (ws + o); o += (size_t)768*256*2;        // 393216
  bf16*  WihT   = (bf16*) (ws + o); o += (size_t)768*256*2;
  bf16*  WhhT   = (bf16*) (ws + o); o += (size_t)768*256*2;
  float* bfused = (float*)(ws + o); o += 1024;
  bf16*  node_bf= (bf16*) (ws + o); o += (size_t)NNODES*256*2;     // 25.6MB
  int*   counts = (int*)  (ws + o); o += (size_t)TT*256*4;
  int*   offs   = (int*)  (ws + o); o += (size_t)TT*256*4;
  int*   cursor = (int*)  (ws + o); o += (size_t)TT*256*4;
  int*   perm   = (int*)  (ws + o); o += (size_t)TT*EE*4;          // 1.92MB
  bf16*  rel_bf = (bf16*) (ws + o); o += (size_t)TT*256*256*2;     // 3.1MB
  float* GI     = (float*)(ws + o); o += (size_t)TT*256*768*4;     // 18.9MB
  float* h      = (float*)(ws + o); o += (size_t)4096*256*4;       // 4.2MB
  bf16*  hbf    = (bf16*) (ws + o); o += (size_t)4096*256*2;       // 2.1MB
  float* gh     = (float*)(ws + o); o += (size_t)4096*768*4;       // 12.6MB
  // total ~69.7 MB

  k_cvt8<<<6250,256,0,stream>>>(node_embeds, node_bf, NNODES*256/8);
  k_build_wbt<<<256,256,0,stream>>>(text_w_W, edge_w_W, WbT);
  k_bias<<<1,256,0,stream>>>(text_w_b, edge_w_W, edge_w_b, bfused);
  k_gruWT<<<768,256,0,stream>>>(gru_Wih, WihT);
  k_gruWT<<<768,256,0,stream>>>(gru_Whh, WhhT);
  k_hist<<<TT,256,0,stream>>>(edge_rel, counts, offs, cursor);
  k_perm<<<dim3((EE+255)/256,TT),256,0,stream>>>(edge_rel, cursor, perm);
  k_edge<<<dim3(256,TT),256,0,stream>>>(node_bf, text_emb, WbT, bfused,
                                        edge_src, edge_dst, counts, offs, perm, rel_bf);
  // GI[t*256+r][0..767] = rel_emb row @ Wih + bih   (M=6144)
  k_gemm<<<dim3(48,6),256,0,stream>>>(rel_bf, WihT, gru_bih, GI);
  for (int s=0; s<SEQQ; ++s){
    if (s > 0)
      k_gemm<<<dim3(32,6),256,0,stream>>>(hbf, WhhT, gru_bhh, gh);   // M=4096
    k_update<<<4096,256,0,stream>>>(GI, gh, gru_bhh, time_idx, h, h, hbf, out, s);
  }
}